// Round 11
// baseline (90.079 us; speedup 1.0000x reference)
//
#include <hip/hip_runtime.h>
#include <math.h>

#define BB 2
#define NN 2048
#define EE 256
#define HH 8
#define DD 32

typedef __attribute__((ext_vector_type(8))) short short8;
typedef __attribute__((ext_vector_type(4))) float f32x4;

__device__ inline unsigned short f2bf(float f) {
  union { float f; unsigned int u; } a; a.f = f;
  unsigned int r = a.u + 0x7FFFu + ((a.u >> 16) & 1u);
  return (unsigned short)(r >> 16);
}
__device__ inline float bf2f(short s) {
  union { unsigned int u; float f; } a;
  a.u = ((unsigned int)(unsigned short)s) << 16;
  return a.f;
}

// ---------------------------------------------------------------------------
// Fused prep kernel, block-range dispatch (all segments independent):
//  blocks [0,256):    cast in_w/out_w -> bf16
//  blocks [256,384):  tau2 = (feat.tau_w[h] + tau_b[h])*log2e; featb = bf16(feat)
//  blocks [384,2432): nds pairwise -dist tiles (reads bbox directly)
// ---------------------------------------------------------------------------
__global__ __launch_bounds__(256) void prep_kernel(const float* __restrict__ bbox,
                                                   const float* __restrict__ feat,
                                                   const float* __restrict__ in_w,
                                                   const float* __restrict__ out_w,
                                                   const float* __restrict__ tau_w,
                                                   const float* __restrict__ tau_b,
                                                   unsigned short* __restrict__ in_wb,
                                                   unsigned short* __restrict__ out_wb,
                                                   float* __restrict__ tau2,
                                                   unsigned short* __restrict__ featb,
                                                   unsigned short* __restrict__ nds) {
  int blk = blockIdx.x;
  int tid = threadIdx.x;
  if (blk < 256) {
    int i = blk * 256 + tid;
    float4 v;
    unsigned short* dst;
    if (i < 49152) {
      v = ((const float4*)in_w)[i];
      dst = in_wb + (size_t)i * 4;
    } else {
      v = ((const float4*)out_w)[i - 49152];
      dst = out_wb + (size_t)(i - 49152) * 4;
    }
    ushort4 u;
    u.x = f2bf(v.x); u.y = f2bf(v.y); u.z = f2bf(v.z); u.w = f2bf(v.w);
    *(ushort4*)dst = u;
  } else if (blk < 384) {
    int idx = (blk - 256) * 256 + tid;
    int row = idx >> 3, h = idx & 7;
    const float4* f = (const float4*)(feat + (size_t)row * EE);
    const float4* w = (const float4*)(tau_w + (size_t)h * EE);
    float s = 0.f;
#pragma unroll 8
    for (int e = 0; e < EE / 4; ++e) {
      float4 a = f[e], b4 = w[e];
      s = fmaf(a.x, b4.x, s);
      s = fmaf(a.y, b4.y, s);
      s = fmaf(a.z, b4.z, s);
      s = fmaf(a.w, b4.w, s);
      if ((e >> 3) == h) {
        ushort4 u;
        u.x = f2bf(a.x); u.y = f2bf(a.y); u.z = f2bf(a.z); u.w = f2bf(a.w);
        *(ushort4*)(featb + (size_t)row * EE + e * 4) = u;
      }
    }
    tau2[idx] = (s + tau_b[h]) * 1.4426950408889634f;
  } else {
    int blk2 = blk - 384;
    int bq = blk2 >> 3;
    int yy = blk2 & 7;
    int b = bq >> 7, qt = bq & 127;
    int w = tid >> 6, lane = tid & 63;
    int q15 = lane & 15, g = lane >> 4;
    int jt = yy * 4 + w;

    const float* bi = bbox + (size_t)(b * NN + qt * 16 + q15) * 4;
    float cix = bi[0], ciy = bi[1];
    const float* bj = bbox + (size_t)(b * NN + jt * 64) * 4;

    float nd[16];
#pragma unroll
    for (int t = 0; t < 4; ++t) {
#pragma unroll
      for (int r = 0; r < 4; ++r) {
        int j = t * 16 + g * 4 + r;
        float2 cj = *(const float2*)(bj + (size_t)j * 4);
        float dx = cix - cj.x, dy = ciy - cj.y;
        nd[t * 4 + r] = -__builtin_amdgcn_sqrtf(fmaf(dy, dy, dx * dx));
      }
    }
    unsigned int u[8];
#pragma unroll
    for (int i = 0; i < 8; ++i)
      asm("v_cvt_pk_bf16_f32 %0, %1, %2" : "=v"(u[i]) : "v"(nd[2 * i]), "v"(nd[2 * i + 1]));
    unsigned short* dst = nds + ((size_t)(b * 128 + qt) * 32 + jt) * 1024 + lane * 16;
    *(uint4*)dst = make_uint4(u[0], u[1], u[2], u[3]);
    *(uint4*)(dst + 8) = make_uint4(u[4], u[5], u[6], u[7]);
  }
}

// ---------------------------------------------------------------------------
// bf16 MFMA GEMM (validated round 7). MODE 0: qkv epilogue -> qb/kh/vpi, with
// Q pre-scaled by (1/sqrt(D))*log2e. MODE 1: out = v + resid (fp32).
// ---------------------------------------------------------------------------
template <int MODE>
__global__ __launch_bounds__(256) void gemm_mfma_kernel(const unsigned short* __restrict__ Ab,
                                                        const unsigned short* __restrict__ Wb,
                                                        const float* __restrict__ bias,
                                                        const float* __restrict__ resid,
                                                        float* __restrict__ Cf,
                                                        unsigned short* __restrict__ qb,
                                                        unsigned short* __restrict__ kh,
                                                        unsigned short* __restrict__ vpi) {
  int tid = threadIdx.x;
  int wv = tid >> 6, lane = tid & 63;
  int p = lane & 15, g = lane >> 4;
  int mW = blockIdx.y * 64 + wv * 16;
  int nB = blockIdx.x * 64;

  const unsigned short* ap = Ab + (size_t)(mW + p) * 256 + g * 8;
  const unsigned short* wp = Wb + (size_t)(nB + p) * 256 + g * 8;

  f32x4 acc[4] = {{0.f, 0.f, 0.f, 0.f}, {0.f, 0.f, 0.f, 0.f},
                  {0.f, 0.f, 0.f, 0.f}, {0.f, 0.f, 0.f, 0.f}};
#pragma unroll
  for (int kk = 0; kk < 8; ++kk) {
    short8 af = *(const short8*)(ap + kk * 32);
#pragma unroll
    for (int t = 0; t < 4; ++t) {
      short8 wf = *(const short8*)(wp + (size_t)t * 16 * 256 + kk * 32);
      acc[t] = __builtin_amdgcn_mfma_f32_16x16x32_bf16(af, wf, acc[t], 0, 0, 0);
    }
  }

#pragma unroll
  for (int t = 0; t < 4; ++t) {
    int n = nB + t * 16 + p;
    float bn = bias[n];
#pragma unroll
    for (int r = 0; r < 4; ++r) {
      int m = mW + g * 4 + r;
      float v = acc[t][r] + bn;
      if (MODE == 1) {
        Cf[(size_t)m * 256 + n] = v + resid[(size_t)m * 256 + n];
      } else {
        int b = m >> 11, tok = m & 2047;
        if (n < 256) {
          qb[(size_t)m * 256 + n] = f2bf(v * 0.25506659272582955f);
        } else if (n < 512) {
          int h = (n - 256) >> 5, d = n & 31;
          kh[((size_t)(b * 8 + h) * NN + tok) * 32 + d] = f2bf(v);
        } else {
          int h = (n - 512) >> 5, d = n & 31;
          int cp = ((tok & 15) << 1) | ((tok >> 4) & 1);
          vpi[(((size_t)(b * 8 + h) * 64 + (tok >> 5)) * 32 + d) * 32 + cp] = f2bf(v);
        }
      }
    }
  }
}

// ---------------------------------------------------------------------------
// MFMA flash attention, QBLK=16 (r8 geometry: grid bh=x, qt=y, 2048 blocks),
// fixed-ref clamped softmax, 4-wave K-split. NEW: FULL register double-buffer
// - K, V and nd frags for tile t+1 are all issued while tile t computes, so
// every global load has a whole tile (~500cy) to land before use.
// ---------------------------------------------------------------------------
__global__ __launch_bounds__(256) void attn_kernel(const unsigned short* __restrict__ qb,
                                                   const unsigned short* __restrict__ kh,
                                                   const unsigned short* __restrict__ vpi,
                                                   const unsigned short* __restrict__ nds,
                                                   const float* __restrict__ tau2,
                                                   unsigned short* __restrict__ ob) {
  __shared__ float accT[4][32][17];
  __shared__ float lT[4][16];
  __shared__ float linv[16];

  int bh = blockIdx.x;
  int b = bh >> 3, h = bh & 7;
  int qtb = blockIdx.y;
  int tid = threadIdx.x;
  int w = tid >> 6;
  int lane = tid & 63;
  int q15 = lane & 15, g = lane >> 4;
  int rowq = b * NN + qtb * 16 + q15;

  short8 qf = *(const short8*)(qb + (size_t)rowq * 256 + h * 32 + g * 8);
  float t2 = tau2[(size_t)rowq * HH + h];

  float l = 0.f;
  f32x4 acc0 = {0.f, 0.f, 0.f, 0.f}, acc1 = {0.f, 0.f, 0.f, 0.f};

  const unsigned short* kb = kh + (size_t)bh * NN * 32 + q15 * 32 + g * 8;
  const unsigned short* vb = vpi + (size_t)bh * NN * 32 + q15 * 32 + g * 8;
  const unsigned short* ndb = nds + (size_t)(b * 128 + qtb) * 32768 + lane * 16;

  int j0base = w * 512;

  short8 kf[2][4];
  short8 vf[2][2][2];
  short8 nf[2][2];

  // prologue: all frags for tile 0
#pragma unroll
  for (int t = 0; t < 4; ++t)
    kf[0][t] = *(const short8*)(kb + (size_t)(j0base + t * 16) * 32);
#pragma unroll
  for (int t2i = 0; t2i < 2; ++t2i)
#pragma unroll
    for (int dh = 0; dh < 2; ++dh)
      vf[0][t2i][dh] = *(const short8*)(vb + (size_t)((j0base >> 5) + t2i) * 1024 + dh * 512);
  nf[0][0] = *(const short8*)(ndb + (size_t)(j0base >> 6) * 1024);
  nf[0][1] = *(const short8*)(ndb + (size_t)(j0base >> 6) * 1024 + 8);

#pragma unroll
  for (int tt = 0; tt < 8; ++tt) {
    const int cur = tt & 1, nxt = cur ^ 1;
    const int j0 = j0base + tt * 64;
    // ---- prefetch ALL of tile tt+1 (K, V, nd) ----
    if (tt < 7) {
      const int j1 = j0 + 64;
#pragma unroll
      for (int t = 0; t < 4; ++t)
        kf[nxt][t] = *(const short8*)(kb + (size_t)(j1 + t * 16) * 32);
#pragma unroll
      for (int t2i = 0; t2i < 2; ++t2i)
#pragma unroll
        for (int dh = 0; dh < 2; ++dh)
          vf[nxt][t2i][dh] = *(const short8*)(vb + (size_t)((j1 >> 5) + t2i) * 1024 + dh * 512);
      nf[nxt][0] = *(const short8*)(ndb + (size_t)(j1 >> 6) * 1024);
      nf[nxt][1] = *(const short8*)(ndb + (size_t)(j1 >> 6) * 1024 + 8);
    }
    // ---- S^T: 4x mfma (A = K rows, B = Q-prescaled) ----
    f32x4 st[4];
#pragma unroll
    for (int t = 0; t < 4; ++t)
      st[t] = __builtin_amdgcn_mfma_f32_16x16x32_bf16(kf[cur][t], qf, (f32x4){0.f, 0.f, 0.f, 0.f}, 0, 0, 0);
    // ---- score + exp2 (fixed reference, clamped) ----
    float p[16], lsum = 0.f;
#pragma unroll
    for (int i = 0; i < 16; ++i) {
      float ndf = bf2f(i < 8 ? nf[cur][0][i] : nf[cur][1][i - 8]);
      float e = fminf(fmaf(ndf, t2, st[i >> 2][i & 3]), 30.f);
      p[i] = __builtin_amdgcn_exp2f(e);
      lsum += p[i];
    }
    l += lsum;
    // ---- pack P -> bf16 frags (pairs keys k,k+16) ----
    union { short8 v; unsigned int u[4]; } pf[2];
#pragma unroll
    for (int t2i = 0; t2i < 2; ++t2i)
#pragma unroll
      for (int wq = 0; wq < 4; ++wq) {
        asm("v_cvt_pk_bf16_f32 %0, %1, %2"
            : "=v"(pf[t2i].u[wq]) : "v"(p[t2i * 8 + wq]), "v"(p[t2i * 8 + 4 + wq]));
      }
    // ---- PV: 4x mfma, acc in O^T layout (col=q, row=d) ----
    acc0 = __builtin_amdgcn_mfma_f32_16x16x32_bf16(vf[cur][0][0], pf[0].v, acc0, 0, 0, 0);
    acc1 = __builtin_amdgcn_mfma_f32_16x16x32_bf16(vf[cur][0][1], pf[0].v, acc1, 0, 0, 0);
    acc0 = __builtin_amdgcn_mfma_f32_16x16x32_bf16(vf[cur][1][0], pf[1].v, acc0, 0, 0, 0);
    acc1 = __builtin_amdgcn_mfma_f32_16x16x32_bf16(vf[cur][1][1], pf[1].v, acc1, 0, 0, 0);
  }

  l += __shfl_xor(l, 16);
  l += __shfl_xor(l, 32);

#pragma unroll
  for (int r = 0; r < 4; ++r) {
    accT[w][g * 4 + r][q15] = acc0[r];
    accT[w][16 + g * 4 + r][q15] = acc1[r];
  }
  if (g == 0) lT[w][q15] = l;
  __syncthreads();

  if (tid < 16) {
    float L = lT[0][tid] + lT[1][tid] + lT[2][tid] + lT[3][tid];
    linv[tid] = 1.f / fmaxf(L, 1e-30f);
  }
  __syncthreads();

#pragma unroll
  for (int ii = 0; ii < 2; ++ii) {
    int i = tid + ii * 256;
    int q = i >> 5, d = i & 31;
    float ov = (accT[0][d][q] + accT[1][d][q] + accT[2][d][q] + accT[3][d][q]) * linv[q];
    ob[((size_t)b * NN + qtb * 16 + q) * EE + h * 32 + d] = f2bf(ov);
  }
}

extern "C" void kernel_launch(void* const* d_in, const int* in_sizes, int n_in,
                              void* d_out, int out_size, void* d_ws, size_t ws_size,
                              hipStream_t stream) {
  const float* bbox  = (const float*)d_in[0];
  const float* feat  = (const float*)d_in[1];
  const float* in_w  = (const float*)d_in[2];
  const float* in_b  = (const float*)d_in[3];
  const float* out_w = (const float*)d_in[4];
  const float* out_b = (const float*)d_in[5];
  const float* tau_w = (const float*)d_in[6];
  const float* tau_b = (const float*)d_in[7];
  float* out = (float*)d_out;

  unsigned short* ob     = (unsigned short*)d_ws;   // 1M bf16
  unsigned short* featb  = ob + 1048576;            // 1M bf16
  unsigned short* qb     = featb + 1048576;         // 1M bf16
  unsigned short* kh     = qb + 1048576;            // 1M bf16
  unsigned short* vpi    = kh + 1048576;            // 1M bf16
  unsigned short* in_wb  = vpi + 1048576;           // 196608 bf16
  unsigned short* out_wb = in_wb + 196608;          // 65536 bf16
  float* tau2 = (float*)(out_wb + 65536);           // 32768 f32
  unsigned short* nds = (unsigned short*)(tau2 + 32768);  // 8,388,608 bf16

  prep_kernel<<<dim3(2432), 256, 0, stream>>>(bbox, feat, in_w, out_w, tau_w, tau_b,
                                              in_wb, out_wb, tau2, featb, nds);
  gemm_mfma_kernel<0><<<dim3(12, 64), 256, 0, stream>>>(featb, in_wb, in_b, nullptr, nullptr,
                                                        qb, kh, vpi);
  attn_kernel<<<dim3(BB * HH, NN / 16), 256, 0, stream>>>(qb, kh, vpi, nds, tau2, ob);
  gemm_mfma_kernel<1><<<dim3(4, 64), 256, 0, stream>>>(ob, out_wb, out_b, feat, out,
                                                       nullptr, nullptr, nullptr);
}

// Round 12
// 89.864 us; speedup vs baseline: 1.0024x; 1.0024x over previous
//
#include <hip/hip_runtime.h>
#include <math.h>

#define BB 2
#define NN 2048
#define EE 256
#define HH 8
#define DD 32

typedef __attribute__((ext_vector_type(8))) short short8;
typedef __attribute__((ext_vector_type(4))) float f32x4;

__device__ inline unsigned short f2bf(float f) {
  union { float f; unsigned int u; } a; a.f = f;
  unsigned int r = a.u + 0x7FFFu + ((a.u >> 16) & 1u);
  return (unsigned short)(r >> 16);
}
__device__ inline float bf2f(short s) {
  union { unsigned int u; float f; } a;
  a.u = ((unsigned int)(unsigned short)s) << 16;
  return a.f;
}

// ---------------------------------------------------------------------------
// Fused prep kernel (nds segment removed — dist now computed inside attn):
//  blocks [0,256):    cast in_w/out_w -> bf16
//  blocks [256,384):  tau2 = (feat.tau_w[h] + tau_b[h])*log2e; featb = bf16(feat)
// ---------------------------------------------------------------------------
__global__ __launch_bounds__(256) void prep_kernel(const float* __restrict__ feat,
                                                   const float* __restrict__ in_w,
                                                   const float* __restrict__ out_w,
                                                   const float* __restrict__ tau_w,
                                                   const float* __restrict__ tau_b,
                                                   unsigned short* __restrict__ in_wb,
                                                   unsigned short* __restrict__ out_wb,
                                                   float* __restrict__ tau2,
                                                   unsigned short* __restrict__ featb) {
  int blk = blockIdx.x;
  int tid = threadIdx.x;
  if (blk < 256) {
    int i = blk * 256 + tid;
    float4 v;
    unsigned short* dst;
    if (i < 49152) {
      v = ((const float4*)in_w)[i];
      dst = in_wb + (size_t)i * 4;
    } else {
      v = ((const float4*)out_w)[i - 49152];
      dst = out_wb + (size_t)(i - 49152) * 4;
    }
    ushort4 u;
    u.x = f2bf(v.x); u.y = f2bf(v.y); u.z = f2bf(v.z); u.w = f2bf(v.w);
    *(ushort4*)dst = u;
  } else {
    int idx = (blk - 256) * 256 + tid;
    int row = idx >> 3, h = idx & 7;
    const float4* f = (const float4*)(feat + (size_t)row * EE);
    const float4* w = (const float4*)(tau_w + (size_t)h * EE);
    float s = 0.f;
#pragma unroll 8
    for (int e = 0; e < EE / 4; ++e) {
      float4 a = f[e], b4 = w[e];
      s = fmaf(a.x, b4.x, s);
      s = fmaf(a.y, b4.y, s);
      s = fmaf(a.z, b4.z, s);
      s = fmaf(a.w, b4.w, s);
      if ((e >> 3) == h) {
        ushort4 u;
        u.x = f2bf(a.x); u.y = f2bf(a.y); u.z = f2bf(a.z); u.w = f2bf(a.w);
        *(ushort4*)(featb + (size_t)row * EE + e * 4) = u;
      }
    }
    tau2[idx] = (s + tau_b[h]) * 1.4426950408889634f;
  }
}

// ---------------------------------------------------------------------------
// bf16 MFMA GEMM (validated round 7). MODE 0: qkv epilogue -> qb/kh/vpi, with
// Q pre-scaled by (1/sqrt(D))*log2e. MODE 1: out = v + resid (fp32).
// ---------------------------------------------------------------------------
template <int MODE>
__global__ __launch_bounds__(256) void gemm_mfma_kernel(const unsigned short* __restrict__ Ab,
                                                        const unsigned short* __restrict__ Wb,
                                                        const float* __restrict__ bias,
                                                        const float* __restrict__ resid,
                                                        float* __restrict__ Cf,
                                                        unsigned short* __restrict__ qb,
                                                        unsigned short* __restrict__ kh,
                                                        unsigned short* __restrict__ vpi) {
  int tid = threadIdx.x;
  int wv = tid >> 6, lane = tid & 63;
  int p = lane & 15, g = lane >> 4;
  int mW = blockIdx.y * 64 + wv * 16;
  int nB = blockIdx.x * 64;

  const unsigned short* ap = Ab + (size_t)(mW + p) * 256 + g * 8;
  const unsigned short* wp = Wb + (size_t)(nB + p) * 256 + g * 8;

  f32x4 acc[4] = {{0.f, 0.f, 0.f, 0.f}, {0.f, 0.f, 0.f, 0.f},
                  {0.f, 0.f, 0.f, 0.f}, {0.f, 0.f, 0.f, 0.f}};
#pragma unroll
  for (int kk = 0; kk < 8; ++kk) {
    short8 af = *(const short8*)(ap + kk * 32);
#pragma unroll
    for (int t = 0; t < 4; ++t) {
      short8 wf = *(const short8*)(wp + (size_t)t * 16 * 256 + kk * 32);
      acc[t] = __builtin_amdgcn_mfma_f32_16x16x32_bf16(af, wf, acc[t], 0, 0, 0);
    }
  }

#pragma unroll
  for (int t = 0; t < 4; ++t) {
    int n = nB + t * 16 + p;
    float bn = bias[n];
#pragma unroll
    for (int r = 0; r < 4; ++r) {
      int m = mW + g * 4 + r;
      float v = acc[t][r] + bn;
      if (MODE == 1) {
        Cf[(size_t)m * 256 + n] = v + resid[(size_t)m * 256 + n];
      } else {
        int b = m >> 11, tok = m & 2047;
        if (n < 256) {
          qb[(size_t)m * 256 + n] = f2bf(v * 0.25506659272582955f);
        } else if (n < 512) {
          int h = (n - 256) >> 5, d = n & 31;
          kh[((size_t)(b * 8 + h) * NN + tok) * 32 + d] = f2bf(v);
        } else {
          int h = (n - 512) >> 5, d = n & 31;
          int cp = ((tok & 15) << 1) | ((tok >> 4) & 1);
          vpi[(((size_t)(b * 8 + h) * 64 + (tok >> 5)) * 32 + d) * 32 + cp] = f2bf(v);
        }
      }
    }
  }
}

// ---------------------------------------------------------------------------
// MFMA flash attention, 8 waves = 8 heads sharing one (b, 16-query) tile.
// grid = 256 blocks x 512 threads. All waves stream the SAME keys in
// lockstep (K/V hit L1 after the first wave); per 64-key tile the block
// cooperatively computes the 1024 -dist values ONCE into LDS (double-
// buffered, frag layout identical to the old nds table). No K-split ->
// no merge. Fixed-ref clamped softmax (validated r8-r11).
// ---------------------------------------------------------------------------
__global__ __launch_bounds__(512) void attn_kernel(const unsigned short* __restrict__ qb,
                                                   const unsigned short* __restrict__ kh,
                                                   const unsigned short* __restrict__ vpi,
                                                   const float* __restrict__ bbox,
                                                   const float* __restrict__ tau2,
                                                   unsigned short* __restrict__ ob) {
  __shared__ unsigned int ndL[2][512];  // 2 x 1024 bf16 (frag layout)

  int bq = blockIdx.x;
  int b = bq >> 7, qt = bq & 127;
  int tid = threadIdx.x;
  int h = tid >> 6;           // wave = head
  int lane = tid & 63;
  int q15 = lane & 15, g = lane >> 4;
  int rowq = b * NN + qt * 16 + q15;
  int bh = b * 8 + h;

  short8 qf = *(const short8*)(qb + (size_t)rowq * 256 + h * 32 + g * 8);
  float t2 = tau2[(size_t)rowq * HH + h];

  // staging-role constants: this thread computes frag values v=2*tid, 2*tid+1
  int lp = tid >> 3;                    // frag lane' (0..63)
  int ii = (tid * 2) & 15;              // frag slot (even)
  int qs = lp & 15, gs = lp >> 4;
  int joff = (ii >> 2) * 16 + gs * 4 + (ii & 3);  // key offset within tile
  const float* bq_ptr = bbox + (size_t)(b * NN + qt * 16 + qs) * 4;
  float cix = bq_ptr[0], ciy = bq_ptr[1];
  const float* bj_base = bbox + (size_t)b * NN * 4;

  float l = 0.f;
  f32x4 acc0 = {0.f, 0.f, 0.f, 0.f}, acc1 = {0.f, 0.f, 0.f, 0.f};

  const unsigned short* kb = kh + (size_t)bh * NN * 32 + q15 * 32 + g * 8;
  const unsigned short* vb = vpi + (size_t)bh * NN * 32 + q15 * 32 + g * 8;

  short8 kf0[4], kf1[4];
  short8 vf0[2][2], vf1[2][2];

  // ---- staging macro: compute nd for tile jj into ndL[buf] ----
#define STAGE_ND(buf, jj)                                                     \
  {                                                                           \
    int j = (jj) * 64 + joff;                                                 \
    float2 c0 = *(const float2*)(bj_base + (size_t)j * 4);                    \
    float2 c1 = *(const float2*)(bj_base + (size_t)(j + 1) * 4);              \
    float dx0 = cix - c0.x, dy0 = ciy - c0.y;                                 \
    float dx1 = cix - c1.x, dy1 = ciy - c1.y;                                 \
    float d0 = -__builtin_amdgcn_sqrtf(fmaf(dy0, dy0, dx0 * dx0));            \
    float d1 = -__builtin_amdgcn_sqrtf(fmaf(dy1, dy1, dx1 * dx1));            \
    unsigned int u;                                                           \
    asm("v_cvt_pk_bf16_f32 %0, %1, %2" : "=v"(u) : "v"(d0), "v"(d1));         \
    ndL[buf][tid] = u;                                                        \
  }

  // ---- compute body for one tile; CUR is a compile-time 0/1 ----
#define TILE_BODY(CUR, TT)                                                    \
  {                                                                           \
    const int j0 = (TT) * 64;                                                 \
    if ((TT) < 31) {                                                          \
      STAGE_ND(CUR ^ 1, (TT) + 1);                                            \
      const int j1 = j0 + 64;                                                 \
      short8* kfn = (CUR) ? kf0 : kf1;                                        \
      _Pragma("unroll") for (int t = 0; t < 4; ++t)                           \
          kfn[t] = *(const short8*)(kb + (size_t)(j1 + t * 16) * 32);         \
      _Pragma("unroll") for (int t2i = 0; t2i < 2; ++t2i)                     \
          _Pragma("unroll") for (int dh = 0; dh < 2; ++dh)                    \
          ((CUR) ? vf0 : vf1)[t2i][dh] =                                      \
              *(const short8*)(vb + (size_t)((j1 >> 5) + t2i) * 1024 + dh * 512); \
    }                                                                         \
    short8* kfc = (CUR) ? kf1 : kf0;                                          \
    f32x4 st[4];                                                              \
    _Pragma("unroll") for (int t = 0; t < 4; ++t)                             \
        st[t] = __builtin_amdgcn_mfma_f32_16x16x32_bf16(                      \
            kfc[t], qf, (f32x4){0.f, 0.f, 0.f, 0.f}, 0, 0, 0);                \
    const short8* ndp = (const short8*)((const unsigned short*)ndL[CUR] + lane * 16); \
    short8 n0 = ndp[0];                                                       \
    short8 n1 = ndp[1];                                                       \
    float p[16], lsum = 0.f;                                                  \
    _Pragma("unroll") for (int i = 0; i < 16; ++i) {                          \
      float ndf = bf2f(i < 8 ? n0[i] : n1[i - 8]);                            \
      float e = fminf(fmaf(ndf, t2, st[i >> 2][i & 3]), 30.f);                \
      p[i] = __builtin_amdgcn_exp2f(e);                                       \
      lsum += p[i];                                                           \
    }                                                                         \
    l += lsum;                                                                \
    union { short8 v; unsigned int u[4]; } pf[2];                             \
    _Pragma("unroll") for (int t2i = 0; t2i < 2; ++t2i)                       \
        _Pragma("unroll") for (int wq = 0; wq < 4; ++wq) {                    \
      asm("v_cvt_pk_bf16_f32 %0, %1, %2"                                      \
          : "=v"(pf[t2i].u[wq])                                               \
          : "v"(p[t2i * 8 + wq]), "v"(p[t2i * 8 + 4 + wq]));                  \
    }                                                                         \
    const short8(*vfc)[2] = (CUR) ? vf1 : vf0;                                \
    acc0 = __builtin_amdgcn_mfma_f32_16x16x32_bf16(vfc[0][0], pf[0].v, acc0, 0, 0, 0); \
    acc1 = __builtin_amdgcn_mfma_f32_16x16x32_bf16(vfc[0][1], pf[0].v, acc1, 0, 0, 0); \
    acc0 = __builtin_amdgcn_mfma_f32_16x16x32_bf16(vfc[1][0], pf[1].v, acc0, 0, 0, 0); \
    acc1 = __builtin_amdgcn_mfma_f32_16x16x32_bf16(vfc[1][1], pf[1].v, acc1, 0, 0, 0); \
    __syncthreads();                                                          \
  }

  // prologue: tile 0 frags + nd
#pragma unroll
  for (int t = 0; t < 4; ++t)
    kf0[t] = *(const short8*)(kb + (size_t)(t * 16) * 32);
#pragma unroll
  for (int t2i = 0; t2i < 2; ++t2i)
#pragma unroll
    for (int dh = 0; dh < 2; ++dh)
      vf0[t2i][dh] = *(const short8*)(vb + (size_t)t2i * 1024 + dh * 512);
  STAGE_ND(0, 0);
  __syncthreads();

  for (int tt = 0; tt < 32; tt += 2) {
    TILE_BODY(0, tt);
    TILE_BODY(1, tt + 1);
  }

  // l: reduce across g-groups (acc holds full key-sum per d,q)
  l += __shfl_xor(l, 16);
  l += __shfl_xor(l, 32);
  float linv = 1.f / fmaxf(l, 1e-30f);

  // epilogue: O^T frag -> ob, two 8B stores per lane
  float o0[4], o1[4];
#pragma unroll
  for (int r = 0; r < 4; ++r) { o0[r] = acc0[r] * linv; o1[r] = acc1[r] * linv; }
  unsigned int w0[2], w1[2];
  asm("v_cvt_pk_bf16_f32 %0, %1, %2" : "=v"(w0[0]) : "v"(o0[0]), "v"(o0[1]));
  asm("v_cvt_pk_bf16_f32 %0, %1, %2" : "=v"(w0[1]) : "v"(o0[2]), "v"(o0[3]));
  asm("v_cvt_pk_bf16_f32 %0, %1, %2" : "=v"(w1[0]) : "v"(o1[0]), "v"(o1[1]));
  asm("v_cvt_pk_bf16_f32 %0, %1, %2" : "=v"(w1[1]) : "v"(o1[2]), "v"(o1[3]));
  unsigned short* op = ob + (size_t)rowq * EE + h * 32;
  *(uint2*)(op + g * 4) = make_uint2(w0[0], w0[1]);
  *(uint2*)(op + 16 + g * 4) = make_uint2(w1[0], w1[1]);
}

extern "C" void kernel_launch(void* const* d_in, const int* in_sizes, int n_in,
                              void* d_out, int out_size, void* d_ws, size_t ws_size,
                              hipStream_t stream) {
  const float* bbox  = (const float*)d_in[0];
  const float* feat  = (const float*)d_in[1];
  const float* in_w  = (const float*)d_in[2];
  const float* in_b  = (const float*)d_in[3];
  const float* out_w = (const float*)d_in[4];
  const float* out_b = (const float*)d_in[5];
  const float* tau_w = (const float*)d_in[6];
  const float* tau_b = (const float*)d_in[7];
  float* out = (float*)d_out;

  unsigned short* ob     = (unsigned short*)d_ws;   // 1M bf16
  unsigned short* featb  = ob + 1048576;            // 1M bf16
  unsigned short* qb     = featb + 1048576;         // 1M bf16
  unsigned short* kh     = qb + 1048576;            // 1M bf16
  unsigned short* vpi    = kh + 1048576;            // 1M bf16
  unsigned short* in_wb  = vpi + 1048576;           // 196608 bf16
  unsigned short* out_wb = in_wb + 196608;          // 65536 bf16
  float* tau2 = (float*)(out_wb + 65536);           // 32768 f32

  prep_kernel<<<dim3(384), 256, 0, stream>>>(feat, in_w, out_w, tau_w, tau_b,
                                             in_wb, out_wb, tau2, featb);
  gemm_mfma_kernel<0><<<dim3(12, 64), 256, 0, stream>>>(featb, in_wb, in_b, nullptr, nullptr,
                                                        qb, kh, vpi);
  attn_kernel<<<dim3(BB * 128), 512, 0, stream>>>(qb, kh, vpi, bbox, tau2, ob);
  gemm_mfma_kernel<1><<<dim3(4, 64), 256, 0, stream>>>(ob, out_wb, out_b, feat, out,
                                                       nullptr, nullptr, nullptr);
}